// Round 5
// baseline (728.267 us; speedup 1.0000x reference)
//
#include <hip/hip_runtime.h>

#define E_ 8
#define C_ 1024
#define H_ 2048
#define B_ 8
#define T_ 1024
#define NGRP 64          // B_*E_
#define NROWS 16384      // B_*T_*K

typedef __bf16 bf16x8 __attribute__((ext_vector_type(8)));
typedef float f32x4 __attribute__((ext_vector_type(4)));
typedef unsigned short u16;

__device__ __forceinline__ u16 f2bf(float f) {
  unsigned u = __float_as_uint(f);
  u += 0x7FFFu + ((u >> 16) & 1u);   // RNE; inputs finite
  return (u16)(u >> 16);
}

// async global->LDS, 16B per lane; lds dst is wave-uniform base + lane*16
__device__ __forceinline__ void gl16(const u16* g, u16* l) {
  __builtin_amdgcn_global_load_lds(
      (const __attribute__((address_space(1))) void*)g,
      (__attribute__((address_space(3))) void*)l, 16, 0, 0);
}

#define MFMA __builtin_amdgcn_mfma_f32_16x16x32_bf16

// ---------- weights: in [E][R][S] f32 -> out [E][S][R] bf16 (transpose) ----------
__global__ __launch_bounds__(256) void k_wt(const float* __restrict__ in,
                                            u16* __restrict__ out, int R, int S) {
  __shared__ u16 tile[64][66];
  int e = blockIdx.z;
  int s0 = blockIdx.x * 64, r0 = blockIdx.y * 64;
  int tx = threadIdx.x & 15, ty = threadIdx.x >> 4;
  const float* src = in + ((size_t)e * R + r0) * S + s0;
  #pragma unroll
  for (int i = 0; i < 4; ++i) {
    int rr = i * 16 + ty;
    float4 v = *reinterpret_cast<const float4*>(src + (size_t)rr * S + tx * 4);
    tile[rr][tx * 4 + 0] = f2bf(v.x);
    tile[rr][tx * 4 + 1] = f2bf(v.y);
    tile[rr][tx * 4 + 2] = f2bf(v.z);
    tile[rr][tx * 4 + 3] = f2bf(v.w);
  }
  __syncthreads();
  u16* dst = out + ((size_t)e * S + s0) * R + r0;
  #pragma unroll
  for (int i = 0; i < 4; ++i) {
    int ss = i * 16 + ty;
    ushort4 o;
    o.x = tile[tx * 4 + 0][ss];
    o.y = tile[tx * 4 + 1][ss];
    o.z = tile[tx * 4 + 2][ss];
    o.w = tile[tx * 4 + 3][ss];
    *reinterpret_cast<ushort4*>(dst + (size_t)ss * R + tx * 4) = o;
  }
}

// ---------- router: one wave per token; emits x bf16 + inverse index ----------
__global__ __launch_bounds__(256) void k_router(const float* __restrict__ x,
                                                const float* __restrict__ rw,
                                                u16* __restrict__ xb,
                                                int* __restrict__ counts,
                                                int* __restrict__ tok,
                                                float* __restrict__ pw,
                                                int* __restrict__ inv) {
  int lane = threadIdx.x & 63;
  int tt = blockIdx.x * 4 + (threadIdx.x >> 6);    // token id 0..8191
  const float* xr = x + (size_t)tt * C_;
  u16* xo = xb + (size_t)tt * C_;
  float acc[8] = {0, 0, 0, 0, 0, 0, 0, 0};
  for (int j = 0; j < 16; ++j) {
    int c = j * 64 + lane;
    float xv = xr[c];
    xo[c] = f2bf(xv);
    float4 r0 = reinterpret_cast<const float4*>(rw + c * 8)[0];
    float4 r1 = reinterpret_cast<const float4*>(rw + c * 8)[1];
    acc[0] += xv * r0.x; acc[1] += xv * r0.y; acc[2] += xv * r0.z; acc[3] += xv * r0.w;
    acc[4] += xv * r1.x; acc[5] += xv * r1.y; acc[6] += xv * r1.z; acc[7] += xv * r1.w;
  }
  #pragma unroll
  for (int e = 0; e < 8; ++e)
    #pragma unroll
    for (int off = 32; off; off >>= 1)
      acc[e] += __shfl_xor(acc[e], off);
  if (lane == 0) {
    int b = tt >> 10, t = tt & (T_ - 1);
    int e0 = 0;
    #pragma unroll
    for (int e = 1; e < 8; ++e) if (acc[e] > acc[e0]) e0 = e;   // ties -> lower idx
    int e1 = -1;
    #pragma unroll
    for (int e = 0; e < 8; ++e)
      if (e != e0 && (e1 < 0 || acc[e] > acc[e1])) e1 = e;
    float l0 = acc[e0], l1 = acc[e1];
    float p0 = 1.f / (1.f + expf(l1 - l0));
    float p1 = 1.f / (1.f + expf(l0 - l1));
    int g0 = b * 8 + e0, g1 = b * 8 + e1;
    int s0 = atomicAdd(&counts[g0], 1);
    tok[g0 * T_ + s0] = t; pw[g0 * T_ + s0] = p0;
    int s1 = atomicAdd(&counts[g1], 1);
    tok[g1 * T_ + s1] = t; pw[g1 * T_ + s1] = p1;
    inv[tt * 2 + 0] = g0 * T_ + s0;
    inv[tt * 2 + 1] = g1 * T_ + s1;
  }
}

// ---------- exclusive prefix over 64 counts ----------
__global__ void k_prefix(const int* __restrict__ counts, int* __restrict__ offsets) {
  if (threadIdx.x == 0) {
    int s = 0;
    for (int i = 0; i < NGRP; ++i) { offsets[i] = s; s += counts[i]; }
    offsets[NGRP] = s;
  }
}

// ---------- GEMM1: inter = (Xe@Wfc+bfc) * silu(Xe@Wg+bg), bf16 out ----------
// BM=256 x BN=128(dual), BK=64, 512 thr (8 waves 4Mx2N), 128KB dbuf LDS.
// ONE vmcnt(0)+barrier per K-tile: tile t's loads issued a full iter earlier
// (no stall), barrier retires reads of the other buffer; then 8 gl16 (t+1) +
// 24 ds_read + 64 MFMA with compiler-scheduled lgkmcnt (m97-optimal).
// Both-sides XOR swizzle -> conflicts 0 (verified r2-r4).
__global__ __launch_bounds__(512) void k_ffn1(
    const u16* __restrict__ xb, const u16* __restrict__ wfcT, const u16* __restrict__ wgT,
    const float* __restrict__ bfc, const float* __restrict__ bg,
    const int* __restrict__ counts, const int* __restrict__ offsets,
    const int* __restrict__ tok, u16* __restrict__ inter) {
  int bid = blockIdx.x;
  int e = bid & 7;                  // XCD pin
  int r = bid >> 3;                 // [0,512)
  int chunk = r >> 7;               // [0,4)   4-coltile chunk (2MB weights -> L2)
  int rr = r & 127;
  int brt = rr >> 2;                // [0,32)  (b, rowtile); col inner (A reuse)
  int col = chunk * 4 + (rr & 3);   // [0,16)
  int b = brt >> 2, rt = brt & 3;
  int g = b * 8 + e;
  int n = counts[g];
  int row0 = rt * 256;
  if (row0 >= n) return;
  int col0 = col * 128;

  __shared__ u16 As[2][256 * 64];   // 2 x 32 KB
  __shared__ u16 Bf[2][128 * 64];   // 2 x 16 KB
  __shared__ u16 Bg[2][128 * 64];   // 2 x 16 KB   total 128 KB

  int tid = threadIdx.x;
  int lane = tid & 63, wid = tid >> 6;   // 8 waves
  int wr = wid >> 1, wc = wid & 1;       // 4M x 2N (64 rows x 64 cols per wave)
  int fr = lane & 15, fq = lane >> 4;
  int q = fr & 7;
  int so0 = (fq ^ q) * 8;                // kk=0 swizzled 16B slot (u16 units)
  int so1 = ((4 + fq) ^ q) * 8;          // kk=1
  bool active = (row0 + wr * 64) < n;    // wave-uniform; tail waves skip compute

  // staging sources, pre-swizzled: chunk ck -> row=ck>>3, src slot=(ck&7)^(row&7)
  const u16* sA[4]; const u16* sF[2]; const u16* sG[2];
  #pragma unroll
  for (int i = 0; i < 4; ++i) {
    int ck = (wid * 4 + i) * 64 + lane;   // [0,2048) -> rows [0,256)
    int row = ck >> 3;
    int kc = ((ck & 7) ^ (row & 7)) * 8;
    int slot = row0 + row;
    int t0 = tok[g * T_ + (slot < n ? slot : n - 1)];
    sA[i] = xb + ((size_t)(b * T_ + t0)) * C_ + kc;
  }
  #pragma unroll
  for (int i = 0; i < 2; ++i) {
    int ck = (wid * 2 + i) * 64 + lane;   // [0,1024) -> rows [0,128)
    int row = ck >> 3;
    int kc = ((ck & 7) ^ (row & 7)) * 8;
    sF[i] = wfcT + ((size_t)e * H_ + col0 + row) * C_ + kc;
    sG[i] = wgT  + ((size_t)e * H_ + col0 + row) * C_ + kc;
  }
  int segA = wid * 4 * 512;   // wave's A staging base (u16)
  int segB = wid * 2 * 512;   // wave's F/G staging base

  f32x4 ah[4][4] = {}; f32x4 ag[4][4] = {};

  // prologue: tile 0 -> buf 0
  #pragma unroll
  for (int i = 0; i < 4; ++i) gl16(sA[i], &As[0][segA + i * 512]);
  #pragma unroll
  for (int i = 0; i < 2; ++i) { gl16(sF[i], &Bf[0][segB + i * 512]);
                                gl16(sG[i], &Bg[0][segB + i * 512]); }

  for (int t = 0; t < 16; ++t) {
    int pb = t & 1;
    // tile t landed (loads issued 1 iter ago); all waves done reading buf pb^1
    asm volatile("s_waitcnt vmcnt(0)\n\ts_barrier" ::: "memory");
    if (t < 15) {
      int kt = (t + 1) * 64;
      u16* Aq = &As[pb ^ 1][0]; u16* Fq = &Bf[pb ^ 1][0]; u16* Gq = &Bg[pb ^ 1][0];
      #pragma unroll
      for (int i = 0; i < 4; ++i) gl16(sA[i] + kt, Aq + segA + i * 512);
      #pragma unroll
      for (int i = 0; i < 2; ++i) { gl16(sF[i] + kt, Fq + segB + i * 512);
                                    gl16(sG[i] + kt, Gq + segB + i * 512); }
    }
    if (active) {
      const u16* Ap = &As[pb][0];
      const u16* Fp = &Bf[pb][0];
      const u16* Gp = &Bg[pb][0];
      // ---- kk=0 cluster (32 MFMA)
      bf16x8 a0[4], f0[4], g0[4];
      #pragma unroll
      for (int m = 0; m < 4; ++m)
        a0[m] = *reinterpret_cast<const bf16x8*>(&Ap[(wr * 64 + m * 16 + fr) * 64 + so0]);
      #pragma unroll
      for (int j = 0; j < 4; ++j) {
        f0[j] = *reinterpret_cast<const bf16x8*>(&Fp[(wc * 64 + j * 16 + fr) * 64 + so0]);
        g0[j] = *reinterpret_cast<const bf16x8*>(&Gp[(wc * 64 + j * 16 + fr) * 64 + so0]);
      }
      __builtin_amdgcn_s_setprio(1);
      #pragma unroll
      for (int m = 0; m < 4; ++m)
        #pragma unroll
        for (int j = 0; j < 4; ++j) {
          ah[m][j] = MFMA(a0[m], f0[j], ah[m][j], 0, 0, 0);
          ag[m][j] = MFMA(a0[m], g0[j], ag[m][j], 0, 0, 0);
        }
      __builtin_amdgcn_s_setprio(0);
      // ---- kk=1 cluster (32 MFMA)
      bf16x8 a1[4], f1[4], g1[4];
      #pragma unroll
      for (int m = 0; m < 4; ++m)
        a1[m] = *reinterpret_cast<const bf16x8*>(&Ap[(wr * 64 + m * 16 + fr) * 64 + so1]);
      #pragma unroll
      for (int j = 0; j < 4; ++j) {
        f1[j] = *reinterpret_cast<const bf16x8*>(&Fp[(wc * 64 + j * 16 + fr) * 64 + so1]);
        g1[j] = *reinterpret_cast<const bf16x8*>(&Gp[(wc * 64 + j * 16 + fr) * 64 + so1]);
      }
      __builtin_amdgcn_s_setprio(1);
      #pragma unroll
      for (int m = 0; m < 4; ++m)
        #pragma unroll
        for (int j = 0; j < 4; ++j) {
          ah[m][j] = MFMA(a1[m], f1[j], ah[m][j], 0, 0, 0);
          ag[m][j] = MFMA(a1[m], g1[j], ag[m][j], 0, 0, 0);
        }
      __builtin_amdgcn_s_setprio(0);
    }
  }

  int base = offsets[g];
  #pragma unroll
  for (int m = 0; m < 4; ++m) {
    #pragma unroll
    for (int rj = 0; rj < 4; ++rj) {
      int slot = row0 + wr * 64 + m * 16 + fq * 4 + rj;
      if (slot < n) {
        size_t rowb = (size_t)(base + slot) * H_;
        #pragma unroll
        for (int j = 0; j < 4; ++j) {
          int hc = col0 + wc * 64 + j * 16 + fr;
          float h  = ah[m][j][rj] + bfc[e * H_ + hc];
          float gp = ag[m][j][rj] + bg[e * H_ + hc];
          inter[rowb + hc] = f2bf(h * gp / (1.f + expf(-gp)));   // h * silu(gp)
        }
      }
    }
  }
}

// ---------- GEMM2: obuf = inter@Wproj + bp  (non-atomic, compacted rows) ----------
// BM=256 x BN=256, BK=64, K=2048, 8 waves 2Mx4N (128x64/wave), 128KB dbuf.
// Same 1-barrier-per-tile schedule; col outer (1MB weight panel L2-resident).
__global__ __launch_bounds__(512) void k_ffn2(
    const u16* __restrict__ inter, const u16* __restrict__ wpT,
    const float* __restrict__ bp,
    const int* __restrict__ counts, const int* __restrict__ offsets,
    float* __restrict__ obuf) {
  int bid = blockIdx.x;
  int e = bid & 7;
  int r = bid >> 3;                 // [0,128)
  int col = r >> 5;                 // [0,4)  col outer: weight panel stays in L2
  int brt = r & 31;                 // [0,32) (b, rowtile) inner
  int b = brt >> 2, rt = brt & 3;
  int g = b * 8 + e;
  int n = counts[g];
  int row0 = rt * 256;
  if (row0 >= n) return;
  int col0 = col * 256;
  int base = offsets[g];

  __shared__ u16 As[2][256 * 64];   // 2 x 32 KB
  __shared__ u16 Bs[2][256 * 64];   // 2 x 32 KB   total 128 KB

  int tid = threadIdx.x;
  int lane = tid & 63, wid = tid >> 6;
  int wr = wid >> 2, wc = wid & 3;       // 2M x 4N (128 rows x 64 cols per wave)
  int fr = lane & 15, fq = lane >> 4;
  int q = fr & 7;
  int so0 = (fq ^ q) * 8;
  int so1 = ((4 + fq) ^ q) * 8;
  bool active = (row0 + wr * 128) < n;

  const u16* sA[4]; const u16* sB[4];
  #pragma unroll
  for (int i = 0; i < 4; ++i) {
    int ck = (wid * 4 + i) * 64 + lane;   // rows [0,256)
    int row = ck >> 3;
    int kc = ((ck & 7) ^ (row & 7)) * 8;
    int slot = row0 + row;
    int rg = base + (slot < n ? slot : n - 1);   // clamp into valid compacted rows
    sA[i] = inter + (size_t)rg * H_ + kc;
    sB[i] = wpT + ((size_t)e * C_ + col0 + row) * H_ + kc;
  }
  int seg = wid * 4 * 512;

  f32x4 acc[8][4] = {};

  // prologue: tile 0 -> buf 0
  #pragma unroll
  for (int i = 0; i < 4; ++i) { gl16(sA[i], &As[0][seg + i * 512]);
                                gl16(sB[i], &Bs[0][seg + i * 512]); }

  for (int t = 0; t < 32; ++t) {
    int pb = t & 1;
    asm volatile("s_waitcnt vmcnt(0)\n\ts_barrier" ::: "memory");
    if (t < 31) {
      int kt = (t + 1) * 64;
      u16* Aq = &As[pb ^ 1][0]; u16* Bq = &Bs[pb ^ 1][0];
      #pragma unroll
      for (int i = 0; i < 4; ++i) { gl16(sA[i] + kt, Aq + seg + i * 512);
                                    gl16(sB[i] + kt, Bq + seg + i * 512); }
    }
    if (active) {
      const u16* Ap = &As[pb][0];
      const u16* Bp = &Bs[pb][0];
      // ---- kk=0 cluster (32 MFMA)
      bf16x8 a0[8], b0[4];
      #pragma unroll
      for (int m = 0; m < 8; ++m)
        a0[m] = *reinterpret_cast<const bf16x8*>(&Ap[(wr * 128 + m * 16 + fr) * 64 + so0]);
      #pragma unroll
      for (int j = 0; j < 4; ++j)
        b0[j] = *reinterpret_cast<const bf16x8*>(&Bp[(wc * 64 + j * 16 + fr) * 64 + so0]);
      __builtin_amdgcn_s_setprio(1);
      #pragma unroll
      for (int m = 0; m < 8; ++m)
        #pragma unroll
        for (int j = 0; j < 4; ++j)
          acc[m][j] = MFMA(a0[m], b0[j], acc[m][j], 0, 0, 0);
      __builtin_amdgcn_s_setprio(0);
      // ---- kk=1 cluster (32 MFMA)
      bf16x8 a1[8], b1[4];
      #pragma unroll
      for (int m = 0; m < 8; ++m)
        a1[m] = *reinterpret_cast<const bf16x8*>(&Ap[(wr * 128 + m * 16 + fr) * 64 + so1]);
      #pragma unroll
      for (int j = 0; j < 4; ++j)
        b1[j] = *reinterpret_cast<const bf16x8*>(&Bp[(wc * 64 + j * 16 + fr) * 64 + so1]);
      __builtin_amdgcn_s_setprio(1);
      #pragma unroll
      for (int m = 0; m < 8; ++m)
        #pragma unroll
        for (int j = 0; j < 4; ++j)
          acc[m][j] = MFMA(a1[m], b1[j], acc[m][j], 0, 0, 0);
      __builtin_amdgcn_s_setprio(0);
    }
  }
  #pragma unroll
  for (int m = 0; m < 8; ++m) {
    #pragma unroll
    for (int rj = 0; rj < 4; ++rj) {
      int slot = row0 + wr * 128 + m * 16 + fq * 4 + rj;
      if (slot < n) {
        float* orow = obuf + (size_t)(base + slot) * C_;
        #pragma unroll
        for (int j = 0; j < 4; ++j) {
          int cc = col0 + wc * 64 + j * 16 + fr;
          orow[cc] = acc[m][j][rj] + bp[e * C_ + cc];
        }
      }
    }
  }
}

// ---------- combine: y[t] = p0*obuf[r0] + p1*obuf[r1] ----------
__global__ __launch_bounds__(256) void k_combine(const float* __restrict__ obuf,
                                                 const int* __restrict__ offsets,
                                                 const int* __restrict__ inv,
                                                 const float* __restrict__ pw,
                                                 float* __restrict__ y) {
  int tt = blockIdx.x;
  int c = threadIdx.x * 4;
  int i0 = inv[tt * 2 + 0], i1 = inv[tt * 2 + 1];
  int r0 = offsets[i0 >> 10] + (i0 & (T_ - 1));
  int r1 = offsets[i1 >> 10] + (i1 & (T_ - 1));
  float p0 = pw[i0], p1 = pw[i1];
  float4 a = *reinterpret_cast<const float4*>(obuf + (size_t)r0 * C_ + c);
  float4 bv = *reinterpret_cast<const float4*>(obuf + (size_t)r1 * C_ + c);
  float4 o;
  o.x = p0 * a.x + p1 * bv.x;
  o.y = p0 * a.y + p1 * bv.y;
  o.z = p0 * a.z + p1 * bv.z;
  o.w = p0 * a.w + p1 * bv.w;
  *reinterpret_cast<float4*>(y + (size_t)tt * C_ + c) = o;
}

extern "C" void kernel_launch(void* const* d_in, const int* in_sizes, int n_in,
                              void* d_out, int out_size, void* d_ws, size_t ws_size,
                              hipStream_t stream) {
  const float* x   = (const float*)d_in[0];
  const float* rw  = (const float*)d_in[1];
  const float* wfc = (const float*)d_in[2];
  const float* bfc = (const float*)d_in[3];
  const float* wg  = (const float*)d_in[4];
  const float* bg  = (const float*)d_in[5];
  const float* wp  = (const float*)d_in[6];
  const float* bp  = (const float*)d_in[7];
  float* y = (float*)d_out;

  char* ws = (char*)d_ws;
  // ws layout (bytes). obuf aliases wfcT+wgT (dead after k_ffn1); total ~177MB.
  const size_t OFF_COUNTS  = 0;                        // 64 ints
  const size_t OFF_OFFSETS = 1024;                     // 65 ints
  const size_t OFF_TOK     = 2048;                     // 256 KB
  const size_t OFF_PW      = OFF_TOK + 262144;         // 256 KB
  const size_t OFF_INV     = OFF_PW + 262144;          // 128 KB
  const size_t OFF_XB      = OFF_INV + 131072;         // 16 MB bf16 x
  const size_t OFF_WPT     = OFF_XB + (size_t)B_ * T_ * C_ * 2;     // 32 MB
  const size_t OFF_INTER   = OFF_WPT + (size_t)E_ * H_ * C_ * 2;    // 64 MB bf16
  const size_t OFF_WFCT    = OFF_INTER + (size_t)NROWS * H_ * 2;    // 32 MB
  const size_t OFF_WGT     = OFF_WFCT + (size_t)E_ * C_ * H_ * 2;   // 32 MB
  const size_t OFF_OBUF    = OFF_WFCT;                 // 64 MB f32, aliases wfcT+wgT
  int*   counts  = (int*)(ws + OFF_COUNTS);
  int*   offsets = (int*)(ws + OFF_OFFSETS);
  int*   tok     = (int*)(ws + OFF_TOK);
  float* pw      = (float*)(ws + OFF_PW);
  int*   inv     = (int*)(ws + OFF_INV);
  u16*   xb      = (u16*)(ws + OFF_XB);
  u16*   wpT     = (u16*)(ws + OFF_WPT);
  u16*   inter   = (u16*)(ws + OFF_INTER);
  u16*   wfcT    = (u16*)(ws + OFF_WFCT);
  u16*   wgT     = (u16*)(ws + OFF_WGT);
  float* obuf    = (float*)(ws + OFF_OBUF);

  hipMemsetAsync(counts, 0, 256, stream);

  k_wt<<<dim3(H_ / 64, C_ / 64, E_), 256, 0, stream>>>(wfc, wfcT, C_, H_);
  k_wt<<<dim3(H_ / 64, C_ / 64, E_), 256, 0, stream>>>(wg, wgT, C_, H_);
  k_wt<<<dim3(C_ / 64, H_ / 64, E_), 256, 0, stream>>>(wp, wpT, H_, C_);
  k_router<<<(B_ * T_) / 4, 256, 0, stream>>>(x, rw, xb, counts, tok, pw, inv);
  k_prefix<<<1, 64, 0, stream>>>(counts, offsets);
  k_ffn1<<<4096, 512, 0, stream>>>(
      xb, wfcT, wgT, bfc, bg, counts, offsets, tok, inter);
  k_ffn2<<<1024, 512, 0, stream>>>(
      inter, wpT, bp, counts, offsets, obuf);
  k_combine<<<B_ * T_, 256, 0, stream>>>(obuf, offsets, inv, pw, y);
  (void)in_sizes; (void)n_in; (void)ws_size;
}

// Round 6
// 676.902 us; speedup vs baseline: 1.0759x; 1.0759x over previous
//
#include <hip/hip_runtime.h>

#define E_ 8
#define C_ 1024
#define H_ 2048
#define B_ 8
#define T_ 1024
#define NGRP 64          // B_*E_
#define NROWS 16384      // B_*T_*K

typedef __bf16 bf16x8 __attribute__((ext_vector_type(8)));
typedef float f32x4 __attribute__((ext_vector_type(4)));
typedef unsigned short u16;

__device__ __forceinline__ u16 f2bf(float f) {
  unsigned u = __float_as_uint(f);
  u += 0x7FFFu + ((u >> 16) & 1u);   // RNE; inputs finite
  return (u16)(u >> 16);
}

// async global->LDS, 16B per lane; lds dst is wave-uniform base + lane*16
__device__ __forceinline__ void gl16(const u16* g, u16* l) {
  __builtin_amdgcn_global_load_lds(
      (const __attribute__((address_space(1))) void*)g,
      (__attribute__((address_space(3))) void*)l, 16, 0, 0);
}

#define MFMA __builtin_amdgcn_mfma_f32_16x16x32_bf16
#define BAR() __builtin_amdgcn_s_barrier()
#define VMCNT(N) asm volatile("s_waitcnt vmcnt(" #N ")" ::: "memory")

// ---------- weights: in [E][R][S] f32 -> out [E][S][R] bf16 (transpose) ----------
__global__ __launch_bounds__(256) void k_wt(const float* __restrict__ in,
                                            u16* __restrict__ out, int R, int S) {
  __shared__ u16 tile[64][66];
  int e = blockIdx.z;
  int s0 = blockIdx.x * 64, r0 = blockIdx.y * 64;
  int tx = threadIdx.x & 15, ty = threadIdx.x >> 4;
  const float* src = in + ((size_t)e * R + r0) * S + s0;
  #pragma unroll
  for (int i = 0; i < 4; ++i) {
    int rr = i * 16 + ty;
    float4 v = *reinterpret_cast<const float4*>(src + (size_t)rr * S + tx * 4);
    tile[rr][tx * 4 + 0] = f2bf(v.x);
    tile[rr][tx * 4 + 1] = f2bf(v.y);
    tile[rr][tx * 4 + 2] = f2bf(v.z);
    tile[rr][tx * 4 + 3] = f2bf(v.w);
  }
  __syncthreads();
  u16* dst = out + ((size_t)e * S + s0) * R + r0;
  #pragma unroll
  for (int i = 0; i < 4; ++i) {
    int ss = i * 16 + ty;
    ushort4 o;
    o.x = tile[tx * 4 + 0][ss];
    o.y = tile[tx * 4 + 1][ss];
    o.z = tile[tx * 4 + 2][ss];
    o.w = tile[tx * 4 + 3][ss];
    *reinterpret_cast<ushort4*>(dst + (size_t)ss * R + tx * 4) = o;
  }
}

// ---------- router: one wave per token; emits x bf16 + inverse index ----------
__global__ __launch_bounds__(256) void k_router(const float* __restrict__ x,
                                                const float* __restrict__ rw,
                                                u16* __restrict__ xb,
                                                int* __restrict__ counts,
                                                int* __restrict__ tok,
                                                float* __restrict__ pw,
                                                int* __restrict__ inv) {
  int lane = threadIdx.x & 63;
  int tt = blockIdx.x * 4 + (threadIdx.x >> 6);    // token id 0..8191
  const float* xr = x + (size_t)tt * C_;
  u16* xo = xb + (size_t)tt * C_;
  float acc[8] = {0, 0, 0, 0, 0, 0, 0, 0};
  for (int j = 0; j < 16; ++j) {
    int c = j * 64 + lane;
    float xv = xr[c];
    xo[c] = f2bf(xv);
    float4 r0 = reinterpret_cast<const float4*>(rw + c * 8)[0];
    float4 r1 = reinterpret_cast<const float4*>(rw + c * 8)[1];
    acc[0] += xv * r0.x; acc[1] += xv * r0.y; acc[2] += xv * r0.z; acc[3] += xv * r0.w;
    acc[4] += xv * r1.x; acc[5] += xv * r1.y; acc[6] += xv * r1.z; acc[7] += xv * r1.w;
  }
  #pragma unroll
  for (int e = 0; e < 8; ++e)
    #pragma unroll
    for (int off = 32; off; off >>= 1)
      acc[e] += __shfl_xor(acc[e], off);
  if (lane == 0) {
    int b = tt >> 10, t = tt & (T_ - 1);
    int e0 = 0;
    #pragma unroll
    for (int e = 1; e < 8; ++e) if (acc[e] > acc[e0]) e0 = e;   // ties -> lower idx
    int e1 = -1;
    #pragma unroll
    for (int e = 0; e < 8; ++e)
      if (e != e0 && (e1 < 0 || acc[e] > acc[e1])) e1 = e;
    float l0 = acc[e0], l1 = acc[e1];
    float p0 = 1.f / (1.f + expf(l1 - l0));
    float p1 = 1.f / (1.f + expf(l0 - l1));
    int g0 = b * 8 + e0, g1 = b * 8 + e1;
    int s0 = atomicAdd(&counts[g0], 1);
    tok[g0 * T_ + s0] = t; pw[g0 * T_ + s0] = p0;
    int s1 = atomicAdd(&counts[g1], 1);
    tok[g1 * T_ + s1] = t; pw[g1 * T_ + s1] = p1;
    inv[tt * 2 + 0] = g0 * T_ + s0;
    inv[tt * 2 + 1] = g1 * T_ + s1;
  }
}

// ---------- exclusive prefix over 64 counts ----------
__global__ void k_prefix(const int* __restrict__ counts, int* __restrict__ offsets) {
  if (threadIdx.x == 0) {
    int s = 0;
    for (int i = 0; i < NGRP; ++i) { offsets[i] = s; s += counts[i]; }
    offsets[NGRP] = s;
  }
}

// ---------- GEMM1: inter = (Xe@Wfc+bfc) * silu(Xe@Wg+bg), bf16 out ----------
// 4-phase derived-waits template (T2+T3+T4+T5). BM=256 x BN=128(dual), BK=64,
// 8 waves 4Mx2N, 128KB dbuf. Per tile, issue order A0..A3,F0,F1,G0,G1 (2/phase).
// Certify-before-barrier-before-read: vmcnt(2) at boundary (A+F), vmcnt(4) at
// P1-tail (G). Never vmcnt(0) except last tile. Reads precede the pacing
// barrier; F/G/A fragments held in regs across phases (P3 reads nothing).
__global__ __launch_bounds__(512) void k_ffn1(
    const u16* __restrict__ xb, const u16* __restrict__ wfcT, const u16* __restrict__ wgT,
    const float* __restrict__ bfc, const float* __restrict__ bg,
    const int* __restrict__ counts, const int* __restrict__ offsets,
    const int* __restrict__ tok, u16* __restrict__ inter) {
  int bid = blockIdx.x;
  int e = bid & 7;                  // XCD pin
  int r = bid >> 3;                 // [0,512)
  int chunk = r >> 7;               // [0,4)  4-coltile chunk (2MB weights -> L2)
  int rr = r & 127;
  int brt = rr >> 2;                // [0,32) (b, rowtile); col inner (A reuse)
  int col = chunk * 4 + (rr & 3);   // [0,16)
  int b = brt >> 2, rt = brt & 3;
  int g = b * 8 + e;
  int n = counts[g];
  int row0 = rt * 256;
  if (row0 >= n) return;
  int col0 = col * 128;

  __shared__ u16 As[2][256 * 64];   // 2 x 32 KB
  __shared__ u16 Bf[2][128 * 64];   // 2 x 16 KB
  __shared__ u16 Bg[2][128 * 64];   // 2 x 16 KB   total 128 KB

  int tid = threadIdx.x;
  int lane = tid & 63, wid = tid >> 6;   // 8 waves
  int wr = wid >> 1, wc = wid & 1;       // 4M x 2N (64 rows x 64 cols, dual)
  int fr = lane & 15, fq = lane >> 4;
  int q = fr & 7;
  int so0 = (fq ^ q) * 8;                // kk=0 swizzled 16B slot (u16 units)
  int so1 = ((4 + fq) ^ q) * 8;          // kk=1
  bool active = (row0 + wr * 64) < n;    // wave-uniform tail skip

  // staging: chunk c = i*8+wid; row = c*8 + (lane>>3); src slot=(lane&7)^(row&7)
  const u16* sA[4]; const u16* sF[2]; const u16* sG[2];
  #pragma unroll
  for (int i = 0; i < 4; ++i) {
    int c = i * 8 + wid;
    int row = c * 8 + (lane >> 3);
    int kc = ((lane & 7) ^ (row & 7)) * 8;
    int slot = row0 + row;
    int t0 = tok[g * T_ + (slot < n ? slot : n - 1)];
    sA[i] = xb + ((size_t)(b * T_ + t0)) * C_ + kc;
  }
  #pragma unroll
  for (int i = 0; i < 2; ++i) {
    int c = i * 8 + wid;
    int row = c * 8 + (lane >> 3);
    int kc = ((lane & 7) ^ (row & 7)) * 8;
    sF[i] = wfcT + ((size_t)e * H_ + col0 + row) * C_ + kc;
    sG[i] = wgT  + ((size_t)e * H_ + col0 + row) * C_ + kc;
  }

  f32x4 ah[4][4] = {}; f32x4 ag[4][4] = {};

  // prologue: tile 0 -> buf 0, exact steady-state order A0..A3,F0,F1,G0,G1
  #pragma unroll
  for (int i = 0; i < 4; ++i) gl16(sA[i], &As[0][(i * 8 + wid) * 512]);
  #pragma unroll
  for (int i = 0; i < 2; ++i) gl16(sF[i], &Bf[0][(i * 8 + wid) * 512]);
  #pragma unroll
  for (int i = 0; i < 2; ++i) gl16(sG[i], &Bg[0][(i * 8 + wid) * 512]);
  VMCNT(2);            // certify A+F of tile 0 (G may be in flight)
  BAR();

  #pragma unroll 2
  for (int t = 0; t < 16; ++t) {
    int pb = t & 1, pbn = pb ^ 1;
    bool st = t < 15;
    int kt = (t + 1) * 64;
    const u16* Ap = &As[pb][0];
    const u16* Fp = &Bf[pb][0];
    const u16* Gp = &Bg[pb][0];
    bf16x8 aA[4][2], fF[4][2], gG[4][2];
    // ---- P0: reads A m01 + F all; stage A0,A1(t+1); mfma h m01
    if (active) {
      #pragma unroll
      for (int m = 0; m < 2; ++m) {
        aA[m][0] = *reinterpret_cast<const bf16x8*>(&Ap[(wr * 64 + m * 16 + fr) * 64 + so0]);
        aA[m][1] = *reinterpret_cast<const bf16x8*>(&Ap[(wr * 64 + m * 16 + fr) * 64 + so1]);
      }
      #pragma unroll
      for (int j = 0; j < 4; ++j) {
        fF[j][0] = *reinterpret_cast<const bf16x8*>(&Fp[(wc * 64 + j * 16 + fr) * 64 + so0]);
        fF[j][1] = *reinterpret_cast<const bf16x8*>(&Fp[(wc * 64 + j * 16 + fr) * 64 + so1]);
      }
    }
    if (st) { gl16(sA[0] + kt, &As[pbn][(0 * 8 + wid) * 512]);
              gl16(sA[1] + kt, &As[pbn][(1 * 8 + wid) * 512]); }
    BAR();
    if (active) {
      __builtin_amdgcn_s_setprio(1);
      #pragma unroll
      for (int m = 0; m < 2; ++m)
        #pragma unroll
        for (int j = 0; j < 4; ++j) {
          ah[m][j] = MFMA(aA[m][0], fF[j][0], ah[m][j], 0, 0, 0);
          ah[m][j] = MFMA(aA[m][1], fF[j][1], ah[m][j], 0, 0, 0);
        }
      __builtin_amdgcn_s_setprio(0);
    }
    BAR();
    // ---- P1: reads A m23; stage A2,A3(t+1); mfma h m23; certify G at tail
    if (active) {
      #pragma unroll
      for (int m = 2; m < 4; ++m) {
        aA[m][0] = *reinterpret_cast<const bf16x8*>(&Ap[(wr * 64 + m * 16 + fr) * 64 + so0]);
        aA[m][1] = *reinterpret_cast<const bf16x8*>(&Ap[(wr * 64 + m * 16 + fr) * 64 + so1]);
      }
    }
    if (st) { gl16(sA[2] + kt, &As[pbn][(2 * 8 + wid) * 512]);
              gl16(sA[3] + kt, &As[pbn][(3 * 8 + wid) * 512]); }
    BAR();
    if (active) {
      __builtin_amdgcn_s_setprio(1);
      #pragma unroll
      for (int m = 2; m < 4; ++m)
        #pragma unroll
        for (int j = 0; j < 4; ++j) {
          ah[m][j] = MFMA(aA[m][0], fF[j][0], ah[m][j], 0, 0, 0);
          ah[m][j] = MFMA(aA[m][1], fF[j][1], ah[m][j], 0, 0, 0);
        }
      __builtin_amdgcn_s_setprio(0);
    }
    if (st) { VMCNT(4); } else { VMCNT(0); }
    BAR();
    // ---- P2: reads G all; stage F0,F1(t+1); mfma g m01
    if (active) {
      #pragma unroll
      for (int j = 0; j < 4; ++j) {
        gG[j][0] = *reinterpret_cast<const bf16x8*>(&Gp[(wc * 64 + j * 16 + fr) * 64 + so0]);
        gG[j][1] = *reinterpret_cast<const bf16x8*>(&Gp[(wc * 64 + j * 16 + fr) * 64 + so1]);
      }
    }
    if (st) { gl16(sF[0] + kt, &Bf[pbn][(0 * 8 + wid) * 512]);
              gl16(sF[1] + kt, &Bf[pbn][(1 * 8 + wid) * 512]); }
    BAR();
    if (active) {
      __builtin_amdgcn_s_setprio(1);
      #pragma unroll
      for (int m = 0; m < 2; ++m)
        #pragma unroll
        for (int j = 0; j < 4; ++j) {
          ag[m][j] = MFMA(aA[m][0], gG[j][0], ag[m][j], 0, 0, 0);
          ag[m][j] = MFMA(aA[m][1], gG[j][1], ag[m][j], 0, 0, 0);
        }
      __builtin_amdgcn_s_setprio(0);
    }
    BAR();
    // ---- P3: no reads; stage G0,G1(t+1); mfma g m23; boundary certify A+F
    if (st) { gl16(sG[0] + kt, &Bg[pbn][(0 * 8 + wid) * 512]);
              gl16(sG[1] + kt, &Bg[pbn][(1 * 8 + wid) * 512]); }
    BAR();
    if (active) {
      __builtin_amdgcn_s_setprio(1);
      #pragma unroll
      for (int m = 2; m < 4; ++m)
        #pragma unroll
        for (int j = 0; j < 4; ++j) {
          ag[m][j] = MFMA(aA[m][0], gG[j][0], ag[m][j], 0, 0, 0);
          ag[m][j] = MFMA(aA[m][1], gG[j][1], ag[m][j], 0, 0, 0);
        }
      __builtin_amdgcn_s_setprio(0);
    }
    if (st) { VMCNT(2); }
    BAR();
  }

  int base = offsets[g];
  #pragma unroll
  for (int m = 0; m < 4; ++m) {
    #pragma unroll
    for (int rj = 0; rj < 4; ++rj) {
      int slot = row0 + wr * 64 + m * 16 + fq * 4 + rj;
      if (slot < n) {
        size_t rowb = (size_t)(base + slot) * H_;
        #pragma unroll
        for (int j = 0; j < 4; ++j) {
          int hc = col0 + wc * 64 + j * 16 + fr;
          float h  = ah[m][j][rj] + bfc[e * H_ + hc];
          float gp = ag[m][j][rj] + bg[e * H_ + hc];
          inter[rowb + hc] = f2bf(h * gp / (1.f + expf(-gp)));   // h * silu(gp)
        }
      }
    }
  }
}

// ---------- GEMM2: obuf = inter@Wproj + bp  (non-atomic, compacted rows) ----------
// Same template. BM=256 x BN=256, BK=64, K=2048, 8 waves 2Mx4N (128x64/wave).
// Issue order B0..B3, A(i0), A(i2), A(i1), A(i3); vmcnt(2) boundary (B + A-half
// for m0..3), vmcnt(4) at P1-tail (A i1,i3 for m4..7). B regs live all phases.
__global__ __launch_bounds__(512) void k_ffn2(
    const u16* __restrict__ inter, const u16* __restrict__ wpT,
    const float* __restrict__ bp,
    const int* __restrict__ counts, const int* __restrict__ offsets,
    float* __restrict__ obuf) {
  int bid = blockIdx.x;
  int e = bid & 7;
  int r = bid >> 3;                 // [0,128)
  int brt = r >> 2;                 // [0,32) (b,rowtile) outer
  int col = r & 3;                  // col inner: 4MB weight e-slice L2-resident
  int b = brt >> 2, rt = brt & 3;
  int g = b * 8 + e;
  int n = counts[g];
  int row0 = rt * 256;
  if (row0 >= n) return;
  int col0 = col * 256;
  int base = offsets[g];

  __shared__ u16 As[2][256 * 64];   // 2 x 32 KB
  __shared__ u16 Bs[2][256 * 64];   // 2 x 32 KB   total 128 KB

  int tid = threadIdx.x;
  int lane = tid & 63, wid = tid >> 6;
  int wr = wid >> 2, wc = wid & 3;       // 2M x 4N
  int fr = lane & 15, fq = lane >> 4;
  int q = fr & 7;
  int so0 = (fq ^ q) * 8;
  int so1 = ((4 + fq) ^ q) * 8;
  bool active = (row0 + wr * 128) < n;

  // A staged in issue order sAo = {i0, i2, i1, i3}: i covers rows i*64..i*64+63.
  // P0/P1 read rows wr*128+0..63 (i = 2*wr in {0,2}); P2/P3 read i in {1,3}.
  const int iord[4] = {0, 2, 1, 3};
  const u16* sAo[4]; int cAo[4];
  #pragma unroll
  for (int k = 0; k < 4; ++k) {
    int i = iord[k];
    int c = i * 8 + wid;
    int row = c * 8 + (lane >> 3);
    int kc = ((lane & 7) ^ (row & 7)) * 8;
    int slot = row0 + row;
    int rg = base + (slot < n ? slot : n - 1);
    sAo[k] = inter + (size_t)rg * H_ + kc;
    cAo[k] = c * 512;
  }
  const u16* sB[4];
  #pragma unroll
  for (int i = 0; i < 4; ++i) {
    int c = i * 8 + wid;
    int row = c * 8 + (lane >> 3);
    int kc = ((lane & 7) ^ (row & 7)) * 8;
    sB[i] = wpT + ((size_t)e * C_ + col0 + row) * H_ + kc;
  }

  f32x4 acc[8][4] = {};

  // prologue: tile 0 -> buf 0, order B0..B3, A(i0), A(i2), A(i1), A(i3)
  #pragma unroll
  for (int i = 0; i < 4; ++i) gl16(sB[i], &Bs[0][(i * 8 + wid) * 512]);
  #pragma unroll
  for (int k = 0; k < 4; ++k) gl16(sAo[k], &As[0][cAo[k]]);
  VMCNT(2);            // certify B all + A(i0,i2)
  BAR();

  #pragma unroll 2
  for (int t = 0; t < 32; ++t) {
    int pb = t & 1, pbn = pb ^ 1;
    bool st = t < 31;
    int kt = (t + 1) * 64;
    const u16* Ap = &As[pb][0];
    const u16* Bp = &Bs[pb][0];
    bf16x8 bB[4][2];
    // ---- P0: reads A m01 + B all; stage B0,B1; mfma m01
    bf16x8 aa0[2][2];
    if (active) {
      #pragma unroll
      for (int m = 0; m < 2; ++m) {
        aa0[m][0] = *reinterpret_cast<const bf16x8*>(&Ap[(wr * 128 + m * 16 + fr) * 64 + so0]);
        aa0[m][1] = *reinterpret_cast<const bf16x8*>(&Ap[(wr * 128 + m * 16 + fr) * 64 + so1]);
      }
      #pragma unroll
      for (int j = 0; j < 4; ++j) {
        bB[j][0] = *reinterpret_cast<const bf16x8*>(&Bp[(wc * 64 + j * 16 + fr) * 64 + so0]);
        bB[j][1] = *reinterpret_cast<const bf16x8*>(&Bp[(wc * 64 + j * 16 + fr) * 64 + so1]);
      }
    }
    if (st) { gl16(sB[0] + kt, &Bs[pbn][(0 * 8 + wid) * 512]);
              gl16(sB[1] + kt, &Bs[pbn][(1 * 8 + wid) * 512]); }
    BAR();
    if (active) {
      __builtin_amdgcn_s_setprio(1);
      #pragma unroll
      for (int m = 0; m < 2; ++m)
        #pragma unroll
        for (int j = 0; j < 4; ++j) {
          acc[m][j] = MFMA(aa0[m][0], bB[j][0], acc[m][j], 0, 0, 0);
          acc[m][j] = MFMA(aa0[m][1], bB[j][1], acc[m][j], 0, 0, 0);
        }
      __builtin_amdgcn_s_setprio(0);
    }
    BAR();
    // ---- P1: reads A m23; stage B2,B3; mfma m23; certify A(i1,i3) at tail
    bf16x8 aa1[2][2];
    if (active) {
      #pragma unroll
      for (int m = 0; m < 2; ++m) {
        aa1[m][0] = *reinterpret_cast<const bf16x8*>(&Ap[(wr * 128 + (2 + m) * 16 + fr) * 64 + so0]);
        aa1[m][1] = *reinterpret_cast<const bf16x8*>(&Ap[(wr * 128 + (2 + m) * 16 + fr) * 64 + so1]);
      }
    }
    if (st) { gl16(sB[2] + kt, &Bs[pbn][(2 * 8 + wid) * 512]);
              gl16(sB[3] + kt, &Bs[pbn][(3 * 8 + wid) * 512]); }
    BAR();
    if (active) {
      __builtin_amdgcn_s_setprio(1);
      #pragma unroll
      for (int m = 0; m < 2; ++m)
        #pragma unroll
        for (int j = 0; j < 4; ++j) {
          acc[2 + m][j] = MFMA(aa1[m][0], bB[j][0], acc[2 + m][j], 0, 0, 0);
          acc[2 + m][j] = MFMA(aa1[m][1], bB[j][1], acc[2 + m][j], 0, 0, 0);
        }
      __builtin_amdgcn_s_setprio(0);
    }
    if (st) { VMCNT(4); } else { VMCNT(0); }
    BAR();
    // ---- P2: reads A m45; stage A(i0),A(i2); mfma m45
    bf16x8 aa2[2][2];
    if (active) {
      #pragma unroll
      for (int m = 0; m < 2; ++m) {
        aa2[m][0] = *reinterpret_cast<const bf16x8*>(&Ap[(wr * 128 + (4 + m) * 16 + fr) * 64 + so0]);
        aa2[m][1] = *reinterpret_cast<const bf16x8*>(&Ap[(wr * 128 + (4 + m) * 16 + fr) * 64 + so1]);
      }
    }
    if (st) { gl16(sAo[0] + kt, &As[pbn][cAo[0]]);
              gl16(sAo[1] + kt, &As[pbn][cAo[1]]); }
    BAR();
    if (active) {
      __builtin_amdgcn_s_setprio(1);
      #pragma unroll
      for (int m = 0; m < 2; ++m)
        #pragma unroll
        for (int j = 0; j < 4; ++j) {
          acc[4 + m][j] = MFMA(aa2[m][0], bB[j][0], acc[4 + m][j], 0, 0, 0);
          acc[4 + m][j] = MFMA(aa2[m][1], bB[j][1], acc[4 + m][j], 0, 0, 0);
        }
      __builtin_amdgcn_s_setprio(0);
    }
    BAR();
    // ---- P3: reads A m67; stage A(i1),A(i3); mfma m67; boundary certify
    bf16x8 aa3[2][2];
    if (active) {
      #pragma unroll
      for (int m = 0; m < 2; ++m) {
        aa3[m][0] = *reinterpret_cast<const bf16x8*>(&Ap[(wr * 128 + (6 + m) * 16 + fr) * 64 + so0]);
        aa3[m][1] = *reinterpret_cast<const bf16x8*>(&Ap[(wr * 128 + (6 + m) * 16 + fr) * 64 + so1]);
      }
    }
    if (st) { gl16(sAo[2] + kt, &As[pbn][cAo[2]]);
              gl16(sAo[3] + kt, &As[pbn][cAo[3]]); }
    BAR();
    if (active) {
      __builtin_amdgcn_s_setprio(1);
      #pragma unroll
      for (int m = 0; m < 2; ++m)
        #pragma unroll
        for (int j = 0; j < 4; ++j) {
          acc[6 + m][j] = MFMA(aa3[m][0], bB[j][0], acc[6 + m][j], 0, 0, 0);
          acc[6 + m][j] = MFMA(aa3[m][1], bB[j][1], acc[6 + m][j], 0, 0, 0);
        }
      __builtin_amdgcn_s_setprio(0);
    }
    if (st) { VMCNT(2); }
    BAR();
  }

  #pragma unroll
  for (int m = 0; m < 8; ++m) {
    #pragma unroll
    for (int rj = 0; rj < 4; ++rj) {
      int slot = row0 + wr * 128 + m * 16 + fq * 4 + rj;
      if (slot < n) {
        float* orow = obuf + (size_t)(base + slot) * C_;
        #pragma unroll
        for (int j = 0; j < 4; ++j) {
          int cc = col0 + wc * 64 + j * 16 + fr;
          orow[cc] = acc[m][j][rj] + bp[e * C_ + cc];
        }
      }
    }
  }
}

// ---------- combine: y[t] = p0*obuf[r0] + p1*obuf[r1] ----------
__global__ __launch_bounds__(256) void k_combine(const float* __restrict__ obuf,
                                                 const int* __restrict__ offsets,
                                                 const int* __restrict__ inv,
                                                 const float* __restrict__ pw,
                                                 float* __restrict__ y) {
  int tt = blockIdx.x;
  int c = threadIdx.x * 4;
  int i0 = inv[tt * 2 + 0], i1 = inv[tt * 2 + 1];
  int r0 = offsets[i0 >> 10] + (i0 & (T_ - 1));
  int r1 = offsets[i1 >> 10] + (i1 & (T_ - 1));
  float p0 = pw[i0], p1 = pw[i1];
  float4 a = *reinterpret_cast<const float4*>(obuf + (size_t)r0 * C_ + c);
  float4 bv = *reinterpret_cast<const float4*>(obuf + (size_t)r1 * C_ + c);
  float4 o;
  o.x = p0 * a.x + p1 * bv.x;
  o.y = p0 * a.y + p1 * bv.y;
  o.z = p0 * a.z + p1 * bv.z;
  o.w = p0 * a.w + p1 * bv.w;
  *reinterpret_cast<float4*>(y + (size_t)tt * C_ + c) = o;
}

extern "C" void kernel_launch(void* const* d_in, const int* in_sizes, int n_in,
                              void* d_out, int out_size, void* d_ws, size_t ws_size,
                              hipStream_t stream) {
  const float* x   = (const float*)d_in[0];
  const float* rw  = (const float*)d_in[1];
  const float* wfc = (const float*)d_in[2];
  const float* bfc = (const float*)d_in[3];
  const float* wg  = (const float*)d_in[4];
  const float* bg  = (const float*)d_in[5];
  const float* wp  = (const float*)d_in[6];
  const float* bp  = (const float*)d_in[7];
  float* y = (float*)d_out;

  char* ws = (char*)d_ws;
  // ws layout (bytes). obuf aliases wfcT+wgT (dead after k_ffn1); total ~177MB.
  const size_t OFF_COUNTS  = 0;                        // 64 ints
  const size_t OFF_OFFSETS = 1024;                     // 65 ints
  const size_t OFF_TOK     = 2048;                     // 256 KB
  const size_t OFF_PW      = OFF_TOK + 262144;         // 256 KB
  const size_t OFF_INV     = OFF_PW + 262144;          // 128 KB
  const size_t OFF_XB      = OFF_INV + 131072;         // 16 MB bf16 x
  const size_t OFF_WPT     = OFF_XB + (size_t)B_ * T_ * C_ * 2;     // 32 MB
  const size_t OFF_INTER   = OFF_WPT + (size_t)E_ * H_ * C_ * 2;    // 64 MB bf16
  const size_t OFF_WFCT    = OFF_INTER + (size_t)NROWS * H_ * 2;    // 32 MB
  const size_t OFF_WGT     = OFF_WFCT + (size_t)E_ * C_ * H_ * 2;   // 32 MB
  const size_t OFF_OBUF    = OFF_WFCT;                 // 64 MB f32, aliases wfcT+wgT
  int*   counts  = (int*)(ws + OFF_COUNTS);
  int*   offsets = (int*)(ws + OFF_OFFSETS);
  int*   tok     = (int*)(ws + OFF_TOK);
  float* pw      = (float*)(ws + OFF_PW);
  int*   inv     = (int*)(ws + OFF_INV);
  u16*   xb      = (u16*)(ws + OFF_XB);
  u16*   wpT     = (u16*)(ws + OFF_WPT);
  u16*   inter   = (u16*)(ws + OFF_INTER);
  u16*   wfcT    = (u16*)(ws + OFF_WFCT);
  u16*   wgT     = (u16*)(ws + OFF_WGT);
  float* obuf    = (float*)(ws + OFF_OBUF);

  hipMemsetAsync(counts, 0, 256, stream);

  k_wt<<<dim3(H_ / 64, C_ / 64, E_), 256, 0, stream>>>(wfc, wfcT, C_, H_);
  k_wt<<<dim3(H_ / 64, C_ / 64, E_), 256, 0, stream>>>(wg, wgT, C_, H_);
  k_wt<<<dim3(C_ / 64, H_ / 64, E_), 256, 0, stream>>>(wp, wpT, H_, C_);
  k_router<<<(B_ * T_) / 4, 256, 0, stream>>>(x, rw, xb, counts, tok, pw, inv);
  k_prefix<<<1, 64, 0, stream>>>(counts, offsets);
  k_ffn1<<<4096, 512, 0, stream>>>(
      xb, wfcT, wgT, bfc, bg, counts, offsets, tok, inter);
  k_ffn2<<<1024, 512, 0, stream>>>(
      inter, wpT, bp, counts, offsets, obuf);
  k_combine<<<B_ * T_, 256, 0, stream>>>(obuf, offsets, inv, pw, y);
  (void)in_sizes; (void)n_in; (void)ws_size;
}

// Round 7
// 550.744 us; speedup vs baseline: 1.3223x; 1.2291x over previous
//
#include <hip/hip_runtime.h>

#define E_ 8
#define C_ 1024
#define H_ 2048
#define B_ 8
#define T_ 1024
#define NGRP 64          // B_*E_
#define NROWS 16384      // B_*T_*K

typedef __bf16 bf16x8 __attribute__((ext_vector_type(8)));
typedef float f32x4 __attribute__((ext_vector_type(4)));
typedef unsigned short u16;

__device__ __forceinline__ u16 f2bf(float f) {
  unsigned u = __float_as_uint(f);
  u += 0x7FFFu + ((u >> 16) & 1u);   // RNE; inputs finite
  return (u16)(u >> 16);
}

// async global->LDS, 16B per lane; lds dst is wave-uniform base + lane*16
__device__ __forceinline__ void gl16(const u16* g, u16* l) {
  __builtin_amdgcn_global_load_lds(
      (const __attribute__((address_space(1))) void*)g,
      (__attribute__((address_space(3))) void*)l, 16, 0, 0);
}

#define MFMA __builtin_amdgcn_mfma_f32_16x16x32_bf16
#define BAR() __builtin_amdgcn_s_barrier()
#define VMCNT(N) asm volatile("s_waitcnt vmcnt(" #N ")" ::: "memory")
#define PRIO1() __builtin_amdgcn_s_setprio(1)
#define PRIO0() __builtin_amdgcn_s_setprio(0)

// ---------- weights: in [E][R][S] f32 -> out [E][S][R] bf16 (transpose) ----------
__global__ __launch_bounds__(256) void k_wt(const float* __restrict__ in,
                                            u16* __restrict__ out, int R, int S) {
  __shared__ u16 tile[64][66];
  int e = blockIdx.z;
  int s0 = blockIdx.x * 64, r0 = blockIdx.y * 64;
  int tx = threadIdx.x & 15, ty = threadIdx.x >> 4;
  const float* src = in + ((size_t)e * R + r0) * S + s0;
  #pragma unroll
  for (int i = 0; i < 4; ++i) {
    int rr = i * 16 + ty;
    float4 v = *reinterpret_cast<const float4*>(src + (size_t)rr * S + tx * 4);
    tile[rr][tx * 4 + 0] = f2bf(v.x);
    tile[rr][tx * 4 + 1] = f2bf(v.y);
    tile[rr][tx * 4 + 2] = f2bf(v.z);
    tile[rr][tx * 4 + 3] = f2bf(v.w);
  }
  __syncthreads();
  u16* dst = out + ((size_t)e * S + s0) * R + r0;
  #pragma unroll
  for (int i = 0; i < 4; ++i) {
    int ss = i * 16 + ty;
    ushort4 o;
    o.x = tile[tx * 4 + 0][ss];
    o.y = tile[tx * 4 + 1][ss];
    o.z = tile[tx * 4 + 2][ss];
    o.w = tile[tx * 4 + 3][ss];
    *reinterpret_cast<ushort4*>(dst + (size_t)ss * R + tx * 4) = o;
  }
}

// ---------- router: one wave per token; emits x bf16 + inverse index ----------
__global__ __launch_bounds__(256) void k_router(const float* __restrict__ x,
                                                const float* __restrict__ rw,
                                                u16* __restrict__ xb,
                                                int* __restrict__ counts,
                                                int* __restrict__ tok,
                                                float* __restrict__ pw,
                                                int* __restrict__ inv) {
  int lane = threadIdx.x & 63;
  int tt = blockIdx.x * 4 + (threadIdx.x >> 6);    // token id 0..8191
  const float* xr = x + (size_t)tt * C_;
  u16* xo = xb + (size_t)tt * C_;
  float acc[8] = {0, 0, 0, 0, 0, 0, 0, 0};
  for (int j = 0; j < 16; ++j) {
    int c = j * 64 + lane;
    float xv = xr[c];
    xo[c] = f2bf(xv);
    float4 r0 = reinterpret_cast<const float4*>(rw + c * 8)[0];
    float4 r1 = reinterpret_cast<const float4*>(rw + c * 8)[1];
    acc[0] += xv * r0.x; acc[1] += xv * r0.y; acc[2] += xv * r0.z; acc[3] += xv * r0.w;
    acc[4] += xv * r1.x; acc[5] += xv * r1.y; acc[6] += xv * r1.z; acc[7] += xv * r1.w;
  }
  #pragma unroll
  for (int e = 0; e < 8; ++e)
    #pragma unroll
    for (int off = 32; off; off >>= 1)
      acc[e] += __shfl_xor(acc[e], off);
  if (lane == 0) {
    int b = tt >> 10, t = tt & (T_ - 1);
    int e0 = 0;
    #pragma unroll
    for (int e = 1; e < 8; ++e) if (acc[e] > acc[e0]) e0 = e;   // ties -> lower idx
    int e1 = -1;
    #pragma unroll
    for (int e = 0; e < 8; ++e)
      if (e != e0 && (e1 < 0 || acc[e] > acc[e1])) e1 = e;
    float l0 = acc[e0], l1 = acc[e1];
    float p0 = 1.f / (1.f + expf(l1 - l0));
    float p1 = 1.f / (1.f + expf(l0 - l1));
    int g0 = b * 8 + e0, g1 = b * 8 + e1;
    int s0 = atomicAdd(&counts[g0], 1);
    tok[g0 * T_ + s0] = t; pw[g0 * T_ + s0] = p0;
    int s1 = atomicAdd(&counts[g1], 1);
    tok[g1 * T_ + s1] = t; pw[g1 * T_ + s1] = p1;
    inv[tt * 2 + 0] = g0 * T_ + s0;
    inv[tt * 2 + 1] = g1 * T_ + s1;
  }
}

// ---------- exclusive prefix over 64 counts ----------
__global__ void k_prefix(const int* __restrict__ counts, int* __restrict__ offsets) {
  if (threadIdx.x == 0) {
    int s = 0;
    for (int i = 0; i < NGRP; ++i) { offsets[i] = s; s += counts[i]; }
    offsets[NGRP] = s;
  }
}

// ---------- GEMM1: inter = (Xe@Wfc+bfc) * silu(Xe@Wg+bg), bf16 out ----------
// m201-faithful port. BM=256 x BN=128(dual F,G), BK=64, 8 waves 4Mx2N (64x64
// dual per wave), 128KB dbuf. LDS in kk-split units {Ak0,Ak1,Fk0,Fk1,Gk0,Gk1};
// per tile 4 phases x {reads-for-phase; stage 2 units of t+1; counted vmcnt;
// barrier; setprio; 16 MFMA}. Wait ledger (FIFO verified): issue order per tile
// p0:[A0k0,A1k0] p1:[Fk0,Gk0] p2:[A0k1,A1k1] p3:[Fk1,Gk1]; waits 6/5/6/5
// certify each unit exactly one barrier before first read. Never drains <4
// except final tile. Intra-row slot XOR swizzle (64B kk-half rows).
__global__ __launch_bounds__(512) void k_ffn1(
    const u16* __restrict__ xb, const u16* __restrict__ wfcT, const u16* __restrict__ wgT,
    const float* __restrict__ bfc, const float* __restrict__ bg,
    const int* __restrict__ counts, const int* __restrict__ offsets,
    const int* __restrict__ tok, u16* __restrict__ inter) {
  int bid = blockIdx.x;
  int e = bid & 7;                  // XCD pin
  int r = bid >> 3;                 // [0,512)
  int chunk = r >> 7;               // [0,4)  4-coltile chunk (2MB weights -> L2)
  int rr = r & 127;
  int brt = rr >> 2;                // [0,32) (b, rowtile); col inner (A reuse)
  int col = chunk * 4 + (rr & 3);   // [0,16)
  int b = brt >> 2, rt = brt & 3;
  int g = b * 8 + e;
  int n = counts[g];
  int row0 = rt * 256;
  if (row0 >= n) return;
  int col0 = col * 128;

  // per buf (u16): Ak0[256*32] Ak1[256*32] Fk0[128*32] Fk1 Gk0 Gk1 = 32768
  __shared__ u16 LDSb[2][32768];    // 128 KB
  const int AK0 = 0, AK1 = 8192, FK0 = 16384, FK1 = 20480, GK0 = 24576, GK1 = 28672;

  int tid = threadIdx.x;
  int lane = tid & 63, wid = tid >> 6;   // 8 waves
  int wr = wid >> 1, wc = wid & 1;       // 4M x 2N, wave 64x64 dual
  int fr = lane & 15, fq = lane >> 4;
  int sw = (fq ^ (fr & 3)) * 8;          // swizzled 16B slot in 64B row (u16)
  bool active = (row0 + wr * 64) < n;    // wave-uniform tail skip

  // staging sources. A-half unit: 1024 chunks, 2 gl16/thread; F/G half: 512, 1.
  const u16* sA[2][2];    // [kk][i]
  #pragma unroll
  for (int i = 0; i < 2; ++i) {
    int cid = (i * 8 + wid) * 64 + lane;     // [0,1024)
    int row = cid >> 2, sl = cid & 3;
    int slot = row0 + row;
    int t0 = tok[g * T_ + (slot < n ? slot : n - 1)];
    const u16* base = xb + ((size_t)(b * T_ + t0)) * C_ + ((sl ^ (row & 3)) * 8);
    sA[0][i] = base;
    sA[1][i] = base + 32;
  }
  const u16* sF[2]; const u16* sG[2];
  {
    int cid = wid * 64 + lane;               // [0,512)
    int row = cid >> 2, sl = cid & 3;
    int kc = (sl ^ (row & 3)) * 8;
    const u16* bf_ = wfcT + ((size_t)e * H_ + col0 + row) * C_ + kc;
    const u16* bg_ = wgT  + ((size_t)e * H_ + col0 + row) * C_ + kc;
    sF[0] = bf_; sF[1] = bf_ + 32;
    sG[0] = bg_; sG[1] = bg_ + 32;
  }
  int dA0 = (0 * 8 + wid) * 512, dA1 = (1 * 8 + wid) * 512;  // u16 dst within unit
  int dB = wid * 512;

  f32x4 ah[4][4] = {}; f32x4 ag[4][4] = {};

  // prologue: tile 0 -> buf 0, order A0k0,A1k0,Fk0,Gk0,A0k1,A1k1,Fk1,Gk1
  {
    u16* L = &LDSb[0][0];
    gl16(sA[0][0], L + AK0 + dA0); gl16(sA[0][1], L + AK0 + dA1);
    gl16(sF[0],    L + FK0 + dB);  gl16(sG[0],    L + GK0 + dB);
    gl16(sA[1][0], L + AK1 + dA0); gl16(sA[1][1], L + AK1 + dA1);
    gl16(sF[1],    L + FK1 + dB);  gl16(sG[1],    L + GK1 + dB);
  }
  VMCNT(5);   // certify Ak0,Fk0 of tile 0
  BAR();

  for (int t = 0; t < 16; ++t) {
    int pb = t & 1;
    bool st = t < 15;
    int kt = (t + 1) * 64;
    const u16* Lc = &LDSb[pb][0];
    u16* Ln = &LDSb[pb ^ 1][0];
    bf16x8 a[4], f[4], gg[4];
    // ---- P0: reads a@kk0 + f@kk0 ; stage Ak0(t+1) ; certify Gk0(t)
    if (active) {
      #pragma unroll
      for (int m = 0; m < 4; ++m)
        a[m] = *reinterpret_cast<const bf16x8*>(&Lc[AK0 + (wr * 64 + m * 16 + fr) * 32 + sw]);
      #pragma unroll
      for (int j = 0; j < 4; ++j)
        f[j] = *reinterpret_cast<const bf16x8*>(&Lc[FK0 + (wc * 64 + j * 16 + fr) * 32 + sw]);
    }
    if (st) { gl16(sA[0][0] + kt, Ln + AK0 + dA0); gl16(sA[0][1] + kt, Ln + AK0 + dA1); }
    if (st) { VMCNT(6); } else { VMCNT(4); }
    BAR();
    if (active) {
      PRIO1();
      #pragma unroll
      for (int m = 0; m < 4; ++m)
        #pragma unroll
        for (int j = 0; j < 4; ++j)
          ah[m][j] = MFMA(a[m], f[j], ah[m][j], 0, 0, 0);
      PRIO0();
    }
    // ---- P1: reads g@kk0 ; stage Fk0,Gk0(t+1) ; certify Ak1,Fk1(t)
    if (active) {
      #pragma unroll
      for (int j = 0; j < 4; ++j)
        gg[j] = *reinterpret_cast<const bf16x8*>(&Lc[GK0 + (wc * 64 + j * 16 + fr) * 32 + sw]);
    }
    if (st) { gl16(sF[0] + kt, Ln + FK0 + dB); gl16(sG[0] + kt, Ln + GK0 + dB); }
    if (st) { VMCNT(5); } else { VMCNT(1); }
    BAR();
    if (active) {
      PRIO1();
      #pragma unroll
      for (int m = 0; m < 4; ++m)
        #pragma unroll
        for (int j = 0; j < 4; ++j)
          ag[m][j] = MFMA(a[m], gg[j], ag[m][j], 0, 0, 0);
      PRIO0();
    }
    // ---- P2: reads a@kk1 + f@kk1 ; stage Ak1(t+1) ; certify Gk1(t)
    if (active) {
      #pragma unroll
      for (int m = 0; m < 4; ++m)
        a[m] = *reinterpret_cast<const bf16x8*>(&Lc[AK1 + (wr * 64 + m * 16 + fr) * 32 + sw]);
      #pragma unroll
      for (int j = 0; j < 4; ++j)
        f[j] = *reinterpret_cast<const bf16x8*>(&Lc[FK1 + (wc * 64 + j * 16 + fr) * 32 + sw]);
    }
    if (st) { gl16(sA[1][0] + kt, Ln + AK1 + dA0); gl16(sA[1][1] + kt, Ln + AK1 + dA1); }
    if (st) { VMCNT(6); } else { VMCNT(0); }
    BAR();
    if (active) {
      PRIO1();
      #pragma unroll
      for (int m = 0; m < 4; ++m)
        #pragma unroll
        for (int j = 0; j < 4; ++j)
          ah[m][j] = MFMA(a[m], f[j], ah[m][j], 0, 0, 0);
      PRIO0();
    }
    // ---- P3: reads g@kk1 ; stage Fk1,Gk1(t+1) ; certify Ak0,Fk0(t+1)
    if (active) {
      #pragma unroll
      for (int j = 0; j < 4; ++j)
        gg[j] = *reinterpret_cast<const bf16x8*>(&Lc[GK1 + (wc * 64 + j * 16 + fr) * 32 + sw]);
    }
    if (st) { gl16(sF[1] + kt, Ln + FK1 + dB); gl16(sG[1] + kt, Ln + GK1 + dB); }
    if (st) { VMCNT(5); }
    BAR();
    if (active) {
      PRIO1();
      #pragma unroll
      for (int m = 0; m < 4; ++m)
        #pragma unroll
        for (int j = 0; j < 4; ++j)
          ag[m][j] = MFMA(a[m], gg[j], ag[m][j], 0, 0, 0);
      PRIO0();
    }
  }

  int base = offsets[g];
  #pragma unroll
  for (int m = 0; m < 4; ++m) {
    #pragma unroll
    for (int rj = 0; rj < 4; ++rj) {
      int slot = row0 + wr * 64 + m * 16 + fq * 4 + rj;
      if (slot < n) {
        size_t rowb = (size_t)(base + slot) * H_;
        #pragma unroll
        for (int j = 0; j < 4; ++j) {
          int hc = col0 + wc * 64 + j * 16 + fr;
          float h  = ah[m][j][rj] + bfc[e * H_ + hc];
          float gp = ag[m][j][rj] + bg[e * H_ + hc];
          inter[rowb + hc] = f2bf(h * gp / (1.f + expf(-gp)));   // h * silu(gp)
        }
      }
    }
  }
}

// ---------- GEMM2: obuf = inter@Wproj + bp  (non-atomic, compacted rows) ----------
// Same template, 2 phases/tile. BM=256 x BN=128, BK=64, K=2048, 8 waves 4Mx2N
// (wave 64x64). Units {Ak0,Ak1,Bk0,Bk1}; issue p0:[A0k0,A1k0,Bk0]
// p1:[A0k1,A1k1,Bk1]; waits vmcnt(3)/vmcnt(3) (ledger verified). 96KB dbuf.
__global__ __launch_bounds__(512) void k_ffn2(
    const u16* __restrict__ inter, const u16* __restrict__ wpT,
    const float* __restrict__ bp,
    const int* __restrict__ counts, const int* __restrict__ offsets,
    float* __restrict__ obuf) {
  int bid = blockIdx.x;
  int e = bid & 7;
  int r = bid >> 3;                 // [0,256)
  int brt = r >> 3;                 // [0,32) (b,rowtile) outer; col inner
  int col = r & 7;                  // [0,8)
  int b = brt >> 2, rt = brt & 3;
  int g = b * 8 + e;
  int n = counts[g];
  int row0 = rt * 256;
  if (row0 >= n) return;
  int col0 = col * 128;
  int base = offsets[g];

  // per buf (u16): Ak0[256*32] Ak1 Bk0[128*32] Bk1 = 24576 u16 = 48 KB
  __shared__ u16 LDSb[2][24576];    // 96 KB
  const int AK0 = 0, AK1 = 8192, BK0 = 16384, BK1 = 20480;

  int tid = threadIdx.x;
  int lane = tid & 63, wid = tid >> 6;
  int wr = wid >> 1, wc = wid & 1;       // 4M x 2N, wave 64x64
  int fr = lane & 15, fq = lane >> 4;
  int sw = (fq ^ (fr & 3)) * 8;
  bool active = (row0 + wr * 64) < n;

  const u16* sA[2][2];
  #pragma unroll
  for (int i = 0; i < 2; ++i) {
    int cid = (i * 8 + wid) * 64 + lane;
    int row = cid >> 2, sl = cid & 3;
    int slot = row0 + row;
    int rg = base + (slot < n ? slot : n - 1);
    const u16* basep = inter + (size_t)rg * H_ + ((sl ^ (row & 3)) * 8);
    sA[0][i] = basep;
    sA[1][i] = basep + 32;
  }
  const u16* sB[2];
  {
    int cid = wid * 64 + lane;
    int row = cid >> 2, sl = cid & 3;
    int kc = (sl ^ (row & 3)) * 8;
    const u16* basep = wpT + ((size_t)e * C_ + col0 + row) * H_ + kc;
    sB[0] = basep; sB[1] = basep + 32;
  }
  int dA0 = (0 * 8 + wid) * 512, dA1 = (1 * 8 + wid) * 512;
  int dB = wid * 512;

  f32x4 acc[4][4] = {};

  // prologue: order A0k0,A1k0,Bk0,A0k1,A1k1,Bk1 -> vmcnt(3) certifies Ak0,Bk0
  {
    u16* L = &LDSb[0][0];
    gl16(sA[0][0], L + AK0 + dA0); gl16(sA[0][1], L + AK0 + dA1);
    gl16(sB[0],    L + BK0 + dB);
    gl16(sA[1][0], L + AK1 + dA0); gl16(sA[1][1], L + AK1 + dA1);
    gl16(sB[1],    L + BK1 + dB);
  }
  VMCNT(3);
  BAR();

  for (int t = 0; t < 32; ++t) {
    int pb = t & 1;
    bool st = t < 31;
    int kt = (t + 1) * 64;
    const u16* Lc = &LDSb[pb][0];
    u16* Ln = &LDSb[pb ^ 1][0];
    bf16x8 a[4], bb[4];
    // ---- P0: reads kk0 ; stage Ak0,Bk0(t+1) ; certify Ak1,Bk1(t)
    if (active) {
      #pragma unroll
      for (int m = 0; m < 4; ++m)
        a[m] = *reinterpret_cast<const bf16x8*>(&Lc[AK0 + (wr * 64 + m * 16 + fr) * 32 + sw]);
      #pragma unroll
      for (int j = 0; j < 4; ++j)
        bb[j] = *reinterpret_cast<const bf16x8*>(&Lc[BK0 + (wc * 64 + j * 16 + fr) * 32 + sw]);
    }
    if (st) { gl16(sA[0][0] + kt, Ln + AK0 + dA0); gl16(sA[0][1] + kt, Ln + AK0 + dA1);
              gl16(sB[0] + kt,    Ln + BK0 + dB); }
    if (st) { VMCNT(3); } else { VMCNT(0); }
    BAR();
    if (active) {
      PRIO1();
      #pragma unroll
      for (int m = 0; m < 4; ++m)
        #pragma unroll
        for (int j = 0; j < 4; ++j)
          acc[m][j] = MFMA(a[m], bb[j], acc[m][j], 0, 0, 0);
      PRIO0();
    }
    // ---- P1: reads kk1 ; stage Ak1,Bk1(t+1) ; certify Ak0,Bk0(t+1)
    if (active) {
      #pragma unroll
      for (int m = 0; m < 4; ++m)
        a[m] = *reinterpret_cast<const bf16x8*>(&Lc[AK1 + (wr * 64 + m * 16 + fr) * 32 + sw]);
      #pragma unroll
      for (int j = 0; j < 4; ++j)
        bb[j] = *reinterpret_cast<const bf16x8*>(&Lc[BK1 + (wc * 64 + j * 16 + fr) * 32 + sw]);
    }
    if (st) { gl16(sA[1][0] + kt, Ln + AK1 + dA0); gl16(sA[1][1] + kt, Ln + AK1 + dA1);
              gl16(sB[1] + kt,    Ln + BK1 + dB); }
    if (st) { VMCNT(3); }
    BAR();
    if (active) {
      PRIO1();
      #pragma unroll
      for (int m = 0; m < 4; ++m)
        #pragma unroll
        for (int j = 0; j < 4; ++j)
          acc[m][j] = MFMA(a[m], bb[j], acc[m][j], 0, 0, 0);
      PRIO0();
    }
  }

  #pragma unroll
  for (int m = 0; m < 4; ++m) {
    #pragma unroll
    for (int rj = 0; rj < 4; ++rj) {
      int slot = row0 + wr * 64 + m * 16 + fq * 4 + rj;
      if (slot < n) {
        float* orow = obuf + (size_t)(base + slot) * C_;
        #pragma unroll
        for (int j = 0; j < 4; ++j) {
          int cc = col0 + wc * 64 + j * 16 + fr;
          orow[cc] = acc[m][j][rj] + bp[e * C_ + cc];
        }
      }
    }
  }
}

// ---------- combine: y[t] = p0*obuf[r0] + p1*obuf[r1] ----------
__global__ __launch_bounds__(256) void k_combine(const float* __restrict__ obuf,
                                                 const int* __restrict__ offsets,
                                                 const int* __restrict__ inv,
                                                 const float* __restrict__ pw,
                                                 float* __restrict__ y) {
  int tt = blockIdx.x;
  int c = threadIdx.x * 4;
  int i0 = inv[tt * 2 + 0], i1 = inv[tt * 2 + 1];
  int r0 = offsets[i0 >> 10] + (i0 & (T_ - 1));
  int r1 = offsets[i1 >> 10] + (i1 & (T_ - 1));
  float p0 = pw[i0], p1 = pw[i1];
  float4 a = *reinterpret_cast<const float4*>(obuf + (size_t)r0 * C_ + c);
  float4 bv = *reinterpret_cast<const float4*>(obuf + (size_t)r1 * C_ + c);
  float4 o;
  o.x = p0 * a.x + p1 * bv.x;
  o.y = p0 * a.y + p1 * bv.y;
  o.z = p0 * a.z + p1 * bv.z;
  o.w = p0 * a.w + p1 * bv.w;
  *reinterpret_cast<float4*>(y + (size_t)tt * C_ + c) = o;
}

extern "C" void kernel_launch(void* const* d_in, const int* in_sizes, int n_in,
                              void* d_out, int out_size, void* d_ws, size_t ws_size,
                              hipStream_t stream) {
  const float* x   = (const float*)d_in[0];
  const float* rw  = (const float*)d_in[1];
  const float* wfc = (const float*)d_in[2];
  const float* bfc = (const float*)d_in[3];
  const float* wg  = (const float*)d_in[4];
  const float* bg  = (const float*)d_in[5];
  const float* wp  = (const float*)d_in[6];
  const float* bp  = (const float*)d_in[7];
  float* y = (float*)d_out;

  char* ws = (char*)d_ws;
  // ws layout (bytes). obuf aliases wfcT+wgT (dead after k_ffn1); total ~177MB.
  const size_t OFF_COUNTS  = 0;                        // 64 ints
  const size_t OFF_OFFSETS = 1024;                     // 65 ints
  const size_t OFF_TOK     = 2048;                     // 256 KB
  const size_t OFF_PW      = OFF_TOK + 262144;         // 256 KB
  const size_t OFF_INV     = OFF_PW + 262144;          // 128 KB
  const size_t OFF_XB      = OFF_INV + 131072;         // 16 MB bf16 x
  const size_t OFF_WPT     = OFF_XB + (size_t)B_ * T_ * C_ * 2;     // 32 MB
  const size_t OFF_INTER   = OFF_WPT + (size_t)E_ * H_ * C_ * 2;    // 64 MB bf16
  const size_t OFF_WFCT    = OFF_INTER + (size_t)NROWS * H_ * 2;    // 32 MB
  const size_t OFF_WGT     = OFF_WFCT + (size_t)E_ * C_ * H_ * 2;   // 32 MB
  const size_t OFF_OBUF    = OFF_WFCT;                 // 64 MB f32, aliases wfcT+wgT
  int*   counts  = (int*)(ws + OFF_COUNTS);
  int*   offsets = (int*)(ws + OFF_OFFSETS);
  int*   tok     = (int*)(ws + OFF_TOK);
  float* pw      = (float*)(ws + OFF_PW);
  int*   inv     = (int*)(ws + OFF_INV);
  u16*   xb      = (u16*)(ws + OFF_XB);
  u16*   wpT     = (u16*)(ws + OFF_WPT);
  u16*   inter   = (u16*)(ws + OFF_INTER);
  u16*   wfcT    = (u16*)(ws + OFF_WFCT);
  u16*   wgT     = (u16*)(ws + OFF_WGT);
  float* obuf    = (float*)(ws + OFF_OBUF);

  hipMemsetAsync(counts, 0, 256, stream);

  k_wt<<<dim3(H_ / 64, C_ / 64, E_), 256, 0, stream>>>(wfc, wfcT, C_, H_);
  k_wt<<<dim3(H_ / 64, C_ / 64, E_), 256, 0, stream>>>(wg, wgT, C_, H_);
  k_wt<<<dim3(C_ / 64, H_ / 64, E_), 256, 0, stream>>>(wp, wpT, H_, C_);
  k_router<<<(B_ * T_) / 4, 256, 0, stream>>>(x, rw, xb, counts, tok, pw, inv);
  k_prefix<<<1, 64, 0, stream>>>(counts, offsets);
  k_ffn1<<<4096, 512, 0, stream>>>(
      xb, wfcT, wgT, bfc, bg, counts, offsets, tok, inter);
  k_ffn2<<<2048, 512, 0, stream>>>(
      inter, wpT, bp, counts, offsets, obuf);
  k_combine<<<B_ * T_, 256, 0, stream>>>(obuf, offsets, inv, pw, y);
  (void)in_sizes; (void)n_in; (void)ws_size;
}